// Round 6
// baseline (1097.195 us; speedup 1.0000x reference)
//
#include <hip/hip_runtime.h>

typedef _Float16 half8 __attribute__((ext_vector_type(8)));
typedef float f32x4 __attribute__((ext_vector_type(4)));

static constexpr int D = 1024;       // VQ_C == C_IN
static constexpr int NCODE = 2048;   // codebook size
static constexpr int MTOK = 16384;   // B * L = 8 * 2048
static constexpr int KIN = 2048;     // C_IN * DS
static constexpr int TLEN = 4096;
static constexpr int CAP = 2048;     // max rescored tokens (est. ~345 flagged)
#define TAU 0.4f

__device__ __forceinline__ void gload16(const void* g, void* l) {
  __builtin_amdgcn_global_load_lds(
      (const __attribute__((address_space(1))) void*)g,
      (__attribute__((address_space(3))) void*)l, 16, 0, 0);
}

#define SBAR()   asm volatile("s_barrier" ::: "memory")
#define WAITV6() asm volatile("s_waitcnt vmcnt(6)" ::: "memory")
#define WAITV4() asm volatile("s_waitcnt vmcnt(4)" ::: "memory")
#define WAITV3() asm volatile("s_waitcnt vmcnt(3)" ::: "memory")
#define WAITV0() asm volatile("s_waitcnt vmcnt(0)" ::: "memory")

__device__ __forceinline__ float key_to_f32(unsigned u) {
  unsigned bits = (u & 0x80000000u) ? (u & 0x7FFFFFFFu) : ~u;
  return __uint_as_float(bits);
}
__device__ __forceinline__ unsigned f32_to_key(float f) {
  unsigned ub = __float_as_uint(f);
  return (ub & 0x80000000u) ? ~ub : (ub | 0x80000000u);
}

// ---------------- pack kernels (unchanged) ----------------
__global__ __launch_bounds__(256) void k_pack_x(const float* __restrict__ x,
                                                _Float16* __restrict__ xh,
                                                _Float16* __restrict__ xl) {
  __shared__ float lds[32][65];
  const int tt0 = blockIdx.x * 64;
  const int cc0 = blockIdx.y * 32;
  const int b = blockIdx.z;
  const float* xb = x + ((size_t)b * D + cc0) * TLEN + tt0;
#pragma unroll
  for (int i = 0; i < 8; ++i) {
    int idx = threadIdx.x + i * 256;
    lds[idx >> 6][idx & 63] = xb[(size_t)(idx >> 6) * TLEN + (idx & 63)];
  }
  __syncthreads();
  const size_t mrow0 = (size_t)b * 2048 + (tt0 >> 1);
#pragma unroll
  for (int i = 0; i < 8; ++i) {
    int idx = threadIdx.x + i * 256;
    int r = idx >> 6, kk = idx & 63;
    float v = lds[kk >> 1][2 * r + (kk & 1)];
    _Float16 h = (_Float16)v;
    size_t off = (mrow0 + r) * (size_t)KIN + (size_t)cc0 * 2 + kk;
    xh[off] = h;
    xl[off] = (_Float16)(v - (float)h);
  }
}

__global__ __launch_bounds__(256) void k_split(const float* __restrict__ s,
                                               _Float16* __restrict__ hi,
                                               _Float16* __restrict__ lo, int n) {
  int i = blockIdx.x * 256 + threadIdx.x;
  if (i < n) {
    float v = s[i];
    _Float16 h = (_Float16)v;
    hi[i] = h;
    lo[i] = (_Float16)(v - (float)h);
  }
}

__global__ __launch_bounds__(256) void k_tohalf(const float* __restrict__ s,
                                                _Float16* __restrict__ hi, int n) {
  int i = blockIdx.x * 256 + threadIdx.x;
  if (i < n) hi[i] = (_Float16)s[i];
}

__global__ __launch_bounds__(256) void k_e2(const float* __restrict__ embed,
                                            float* __restrict__ e2c) {
  int row = blockIdx.x * 4 + (threadIdx.x >> 6);
  int lane = threadIdx.x & 63;
  const float* er = embed + (size_t)row * D;
  double s = 0.0;
  for (int i = lane; i < D; i += 64) { double v = er[i]; s += v * v; }
#pragma unroll
  for (int mk = 1; mk < 64; mk <<= 1) s += __shfl_xor(s, mk, 64);
  if (lane == 0) e2c[row] = (float)(s - 1024.0);
}

// ---------------- tok GEMM: 3-product split (R4 structure, unchanged) ----------------
template <int KDIM, int LOG_GX>
__global__ __launch_bounds__(512, 2) void k_gemm_tok3(
    const _Float16* __restrict__ Ah_, const _Float16* __restrict__ Al_,
    const _Float16* __restrict__ Bh_, const _Float16* __restrict__ Bl_,
    const float* __restrict__ vec,
    _Float16* __restrict__ outh, _Float16* __restrict__ outl,
    float* __restrict__ t2) {
  __shared__ _Float16 lds[3 * 24576];
  const int nwg = gridDim.x;
  const int bid = blockIdx.x;
  const int q = nwg >> 3;
  const int b2 = (bid & 7) * q + (bid >> 3);
  const int n0 = (b2 & ((1 << LOG_GX) - 1)) * 128;
  const int m0 = (b2 >> LOG_GX) * 256;

  const int tid = threadIdx.x, lane = tid & 63, w = tid >> 6;
  const int wr = w >> 1, wc = w & 1, lr = lane & 15, lk = lane >> 4;
  constexpr int NT = KDIM / 32;

  const int cswz8 = (((lane & 3) ^ ((lane >> 3) & 3))) * 8;
  const int rswz8 = (lk ^ ((lr >> 1) & 3)) * 8;

  f32x4 acc[4][4] = {};
  half8 ahA[4], bhA[4], ahB[4], bhB[4], al[4], bl[4];

  auto stageA2 = [&](const _Float16* __restrict__ src, int k0, char* regionBase) {
    int slot0 = w * 64 + lane;
    gload16(src + (size_t)(m0 + (slot0 >> 2)) * KDIM + k0 + cswz8,
            regionBase + w * 1024);
    int slot1 = slot0 + 512;
    gload16(src + (size_t)(m0 + (slot1 >> 2)) * KDIM + k0 + cswz8,
            regionBase + w * 1024 + 8192);
  };
  auto stageB2 = [&](int k0, char* stageBase) {
    int slot = w * 64 + lane;
    size_t go = (size_t)(n0 + (slot >> 2)) * KDIM + k0 + cswz8;
    gload16(Bh_ + go, stageBase + 32768 + w * 1024);
    gload16(Bl_ + go, stageBase + 40960 + w * 1024);
  };
  auto stageAll = [&](int t, int c) {
    char* sb = (char*)lds + c * 49152;
    stageA2(Ah_, t * 32, sb);
    stageA2(Al_, t * 32, sb + 16384);
    stageB2(t * 32, sb);
  };

  int c0 = 0, c1 = 1, c2 = 2;
  stageAll(0, 0);
  stageAll(1, 1);
  WAITV6();
  SBAR();
#pragma unroll
  for (int f = 0; f < 4; ++f) {
    ahA[f] = *(const half8*)(lds + (wr * 64 + f * 16 + lr) * 32 + rswz8);
    bhA[f] = *(const half8*)(lds + 16384 + (wc * 64 + f * 16 + lr) * 32 + rswz8);
  }

  auto tile_body = [&](int t, half8 (&ahC)[4], half8 (&bhC)[4],
                       half8 (&ahN)[4], half8 (&bhN)[4]) {
    const _Float16* sb = lds + c0 * 24576;
    char* dstb = (char*)lds + c2 * 49152;
    const bool st = (t + 2) < NT;
    const int ks = (t + 2) * 32;

#pragma unroll
    for (int f = 0; f < 4; ++f)
      bl[f] = *(const half8*)(sb + 20480 + (wc * 64 + f * 16 + lr) * 32 + rswz8);
    if (st) stageA2(Ah_, ks, dstb);
    SBAR();
    __builtin_amdgcn_s_setprio(1);
#pragma unroll
    for (int fm = 0; fm < 4; ++fm)
#pragma unroll
      for (int fn = 0; fn < 4; ++fn)
        acc[fm][fn] = __builtin_amdgcn_mfma_f32_16x16x32_f16(ahC[fm], bhC[fn], acc[fm][fn], 0, 0, 0);
    __builtin_amdgcn_s_setprio(0);
    SBAR();

#pragma unroll
    for (int f = 0; f < 4; ++f)
      al[f] = *(const half8*)(sb + 8192 + (wr * 64 + f * 16 + lr) * 32 + rswz8);
    if (st) stageA2(Al_, ks, dstb + 16384);
    WAITV4();
    SBAR();
    __builtin_amdgcn_s_setprio(1);
#pragma unroll
    for (int fm = 0; fm < 4; ++fm)
#pragma unroll
      for (int fn = 0; fn < 4; ++fn)
        acc[fm][fn] = __builtin_amdgcn_mfma_f32_16x16x32_f16(ahC[fm], bl[fn], acc[fm][fn], 0, 0, 0);
    __builtin_amdgcn_s_setprio(0);
    SBAR();

    if (t + 1 < NT) {
      const _Float16* sb1 = lds + c1 * 24576;
#pragma unroll
      for (int f = 0; f < 4; ++f) {
        ahN[f] = *(const half8*)(sb1 + (wr * 64 + f * 16 + lr) * 32 + rswz8);
        bhN[f] = *(const half8*)(sb1 + 16384 + (wc * 64 + f * 16 + lr) * 32 + rswz8);
      }
    }
    if (st) stageB2(ks, dstb);
    SBAR();
    __builtin_amdgcn_s_setprio(1);
#pragma unroll
    for (int fm = 0; fm < 4; ++fm)
#pragma unroll
      for (int fn = 0; fn < 4; ++fn)
        acc[fm][fn] = __builtin_amdgcn_mfma_f32_16x16x32_f16(al[fm], bhC[fn], acc[fm][fn], 0, 0, 0);
    __builtin_amdgcn_s_setprio(0);
    if (st) { WAITV6(); } else if (t + 1 < NT) { WAITV0(); }
    SBAR();

    int tmp = c0; c0 = c1; c1 = c2; c2 = tmp;
  };

  for (int tt = 0; tt < NT; tt += 2) {
    tile_body(tt,     ahA, bhA, ahB, bhB);
    tile_body(tt + 1, ahB, bhB, ahA, bhA);
  }

  // epilogue: +b_in, split to f16 hi/lo, accumulate ||t||^2 per token row
#pragma unroll
  for (int fm = 0; fm < 4; ++fm) {
#pragma unroll
    for (int j = 0; j < 4; ++j) {
      int row = wr * 64 + fm * 16 + lk * 4 + j;
      size_t m = (size_t)m0 + row;
      float v2 = 0.f;
#pragma unroll
      for (int fn = 0; fn < 4; ++fn) {
        int col = n0 + wc * 64 + fn * 16 + lr;
        float v = acc[fm][fn][j] + vec[col];
        v2 += v * v;
        _Float16 h = (_Float16)v;
        outh[m * D + col] = h;
        outl[m * D + col] = (_Float16)(v - (float)h);
      }
#pragma unroll
      for (int mk = 1; mk < 16; mk <<= 1) v2 += __shfl_xor(v2, mk, 64);
      if (lr == 0) atomicAdd(&t2[m], v2);
    }
  }
}

// ---------------- score pass-1: single hh product + top-2 margin ----------------
// 256x128 tile, 512 thr, hi-only staging (24KB/tile, 3 buffers = 72KB -> 2 blocks/CU).
// R6 fix: per-WAVE result slot skKey/skSnd[m*32 + nb*2 + wc] — the R5 version had
// two waves (wc=0/1, same rows) racing a plain store to the same slot.
__global__ __launch_bounds__(512, 4) void k_score1(
    const _Float16* __restrict__ Ah_, const _Float16* __restrict__ Bh_,
    const float* __restrict__ e2c,
    unsigned long long* __restrict__ skKey, float* __restrict__ skSnd) {
  __shared__ _Float16 lds[3 * 12288];  // per buf: A[256x32] 16KB @0, B[128x32] 8KB @16384B
  const int nwg = gridDim.x, bid = blockIdx.x, q = nwg >> 3;
  const int b2 = (bid & 7) * q + (bid >> 3);
  const int nb = b2 & 15;
  const int n0 = nb * 128, m0 = (b2 >> 4) * 256;
  const int tid = threadIdx.x, lane = tid & 63, w = tid >> 6;
  const int wr = w >> 1, wc = w & 1, lr = lane & 15, lk = lane >> 4;
  constexpr int NT = D / 32;
  const int cswz8 = (((lane & 3) ^ ((lane >> 3) & 3))) * 8;
  const int rswz8 = (lk ^ ((lr >> 1) & 3)) * 8;

  f32x4 acc[4][4] = {};

  auto stage = [&](int t, int c) {  // 3 loads/thread
    char* sb = (char*)lds + c * 24576;
    const int k0 = t * 32;
    int slot0 = w * 64 + lane;
    gload16(Ah_ + (size_t)(m0 + (slot0 >> 2)) * D + k0 + cswz8, sb + w * 1024);
    int slot1 = slot0 + 512;
    gload16(Ah_ + (size_t)(m0 + (slot1 >> 2)) * D + k0 + cswz8, sb + w * 1024 + 8192);
    gload16(Bh_ + (size_t)(n0 + (slot0 >> 2)) * D + k0 + cswz8, sb + 16384 + w * 1024);
  };

  stage(0, 0);
  stage(1, 1);
  WAITV3();
  SBAR();

  int c0 = 0, c1 = 1, c2 = 2;
  for (int t = 0; t < NT; ++t) {
    const _Float16* sb = lds + c0 * 12288;
    half8 ah[4], bh[4];
#pragma unroll
    for (int f = 0; f < 4; ++f) {
      ah[f] = *(const half8*)(sb + (wr * 64 + f * 16 + lr) * 32 + rswz8);
      bh[f] = *(const half8*)(sb + 8192 + (wc * 64 + f * 16 + lr) * 32 + rswz8);
    }
    const bool st = (t + 2) < NT;
    if (st) stage(t + 2, c2);
    SBAR();
    __builtin_amdgcn_s_setprio(1);
#pragma unroll
    for (int fm = 0; fm < 4; ++fm)
#pragma unroll
      for (int fn = 0; fn < 4; ++fn)
        acc[fm][fn] = __builtin_amdgcn_mfma_f32_16x16x32_f16(ah[fm], bh[fn], acc[fm][fn], 0, 0, 0);
    __builtin_amdgcn_s_setprio(0);
    if (st) { WAITV3(); } else if (t + 1 < NT) { WAITV0(); }
    SBAR();
    int tmp = c0; c0 = c1; c1 = c2; c2 = tmp;
  }

  // epilogue: per row: top-2 of mval over THIS WAVE's 64 codes -> private slot
#pragma unroll
  for (int fm = 0; fm < 4; ++fm) {
#pragma unroll
    for (int j = 0; j < 4; ++j) {
      int row = wr * 64 + fm * 16 + lk * 4 + j;
      size_t m = (size_t)m0 + row;
      float b1 = 3.4e38f, bb2 = 3.4e38f;
      int i1 = 0x7FFFFFFF;
#pragma unroll
      for (int fn = 0; fn < 4; ++fn) {
        int col = n0 + wc * 64 + fn * 16 + lr;
        float mv = e2c[col] - 2.0f * acc[fm][fn][j];
        if (mv < b1) { bb2 = b1; b1 = mv; i1 = col; }
        else if (mv < bb2) { bb2 = mv; }
      }
#pragma unroll
      for (int mk = 1; mk < 16; mk <<= 1) {
        float ob1 = __shfl_xor(b1, mk, 64);
        float ob2 = __shfl_xor(bb2, mk, 64);
        int oi = __shfl_xor(i1, mk, 64);
        if (ob1 < b1) { bb2 = fminf(b1, ob2); b1 = ob1; i1 = oi; }
        else { bb2 = fminf(bb2, ob1); }
      }
      if (lr == 0) {
        unsigned long long key = ((unsigned long long)f32_to_key(b1) << 32) | (unsigned)i1;
        skKey[m * 32 + nb * 2 + wc] = key;
        skSnd[m * 32 + nb * 2 + wc] = bb2;
      }
    }
  }
}

// ---------------- flag: global top-2 over 32 slots, margin test, compact ----------------
__global__ __launch_bounds__(256) void k_flag(const unsigned long long* __restrict__ skKey,
                                              const float* __restrict__ skSnd,
                                              unsigned long long* __restrict__ keys,
                                              int* __restrict__ list, int* __restrict__ counter) {
  int m = blockIdx.x * 256 + threadIdx.x;
  unsigned long long best = ~0ull;
  int bsl = 0;
#pragma unroll
  for (int sl = 0; sl < 32; ++sl) {
    unsigned long long k = skKey[(size_t)m * 32 + sl];
    if (k < best) { best = k; bsl = sl; }
  }
  float b1 = key_to_f32((unsigned)(best >> 32));
  float second = skSnd[(size_t)m * 32 + bsl];
#pragma unroll
  for (int sl = 0; sl < 32; ++sl) {
    if (sl != bsl) second = fminf(second, key_to_f32((unsigned)(skKey[(size_t)m * 32 + sl] >> 32)));
  }
  keys[m] = best;
  if (second - b1 < TAU) {
    int p = atomicAdd(counter, 1);
    if (p < CAP) list[p] = m;
  }
}

// ---------------- rescore: 3-product exact scoring of flagged tokens ----------------
__global__ __launch_bounds__(256) void k_rescore(
    const _Float16* __restrict__ tokh, const _Float16* __restrict__ tokl,
    const _Float16* __restrict__ eh, const _Float16* __restrict__ el,
    const float* __restrict__ e2c, const int* __restrict__ list,
    unsigned long long* __restrict__ keys2) {
  __shared__ _Float16 sAh[128 * 32], sAl[128 * 32], sBh[128 * 32], sBl[128 * 32];
  const int n0 = blockIdx.x * 128, m0 = blockIdx.y * 128;
  const int tid = threadIdx.x, lane = tid & 63, w = tid >> 6;
  const int wr = w >> 1, wc = w & 1, lr = lane & 15, lk = lane >> 4;
  f32x4 acc[4][4] = {};

  const int g0 = w * 128 + lane, g1 = g0 + 64;
  const int rA0 = g0 >> 2, cA0 = g0 & 3, rA1 = g1 >> 2, cA1 = g1 & 3;
  const int lb0 = (w * 128) * 16, lb1 = (w * 128 + 64) * 16;
  const int tk0 = list[m0 + rA0], tk1 = list[m0 + rA1];

  for (int kt = 0; kt < D / 32; ++kt) {
    const int k0 = kt * 32;
    gload16(tokh + (size_t)tk0 * D + k0 + cA0 * 8, (char*)sAh + lb0);
    gload16(tokh + (size_t)tk1 * D + k0 + cA1 * 8, (char*)sAh + lb1);
    gload16(tokl + (size_t)tk0 * D + k0 + cA0 * 8, (char*)sAl + lb0);
    gload16(tokl + (size_t)tk1 * D + k0 + cA1 * 8, (char*)sAl + lb1);
    gload16(eh + (size_t)(n0 + rA0) * D + k0 + cA0 * 8, (char*)sBh + lb0);
    gload16(eh + (size_t)(n0 + rA1) * D + k0 + cA1 * 8, (char*)sBh + lb1);
    gload16(el + (size_t)(n0 + rA0) * D + k0 + cA0 * 8, (char*)sBl + lb0);
    gload16(el + (size_t)(n0 + rA1) * D + k0 + cA1 * 8, (char*)sBl + lb1);
    __syncthreads();
    half8 ah[4], al2[4], bh[4], bl2[4];
#pragma unroll
    for (int f = 0; f < 4; ++f) {
      ah[f]  = *(const half8*)(sAh + (wr * 64 + f * 16 + lr) * 32 + lk * 8);
      al2[f] = *(const half8*)(sAl + (wr * 64 + f * 16 + lr) * 32 + lk * 8);
      bh[f]  = *(const half8*)(sBh + (wc * 64 + f * 16 + lr) * 32 + lk * 8);
      bl2[f] = *(const half8*)(sBl + (wc * 64 + f * 16 + lr) * 32 + lk * 8);
    }
#pragma unroll
    for (int fm = 0; fm < 4; ++fm)
#pragma unroll
      for (int fn = 0; fn < 4; ++fn) {
        acc[fm][fn] = __builtin_amdgcn_mfma_f32_16x16x32_f16(ah[fm], bh[fn], acc[fm][fn], 0, 0, 0);
        acc[fm][fn] = __builtin_amdgcn_mfma_f32_16x16x32_f16(ah[fm], bl2[fn], acc[fm][fn], 0, 0, 0);
        acc[fm][fn] = __builtin_amdgcn_mfma_f32_16x16x32_f16(al2[fm], bh[fn], acc[fm][fn], 0, 0, 0);
      }
    __syncthreads();
  }
#pragma unroll
  for (int fm = 0; fm < 4; ++fm) {
#pragma unroll
    for (int j = 0; j < 4; ++j) {
      int row = wr * 64 + fm * 16 + lk * 4 + j;
      int tm = list[m0 + row];
      float best = 3.4e38f;
      int bidx = 0x7FFFFFFF;
#pragma unroll
      for (int fn = 0; fn < 4; ++fn) {
        int col = n0 + wc * 64 + fn * 16 + lr;
        float mv = e2c[col] - 2.0f * acc[fm][fn][j];
        if (mv < best) { best = mv; bidx = col; }
      }
#pragma unroll
      for (int mk = 1; mk < 16; mk <<= 1) {
        float ob = __shfl_xor(best, mk, 64);
        int oi = __shfl_xor(bidx, mk, 64);
        if (ob < best || (ob == best && oi < bidx)) { best = ob; bidx = oi; }
      }
      if (lr == 0) {
        unsigned long long key = ((unsigned long long)f32_to_key(best) << 32) | (unsigned)bidx;
        atomicMin(&keys2[tm], key);
      }
    }
  }
}

__global__ __launch_bounds__(256) void k_merge(unsigned long long* __restrict__ keys,
                                               const unsigned long long* __restrict__ keys2) {
  int m = blockIdx.x * 256 + threadIdx.x;
  unsigned long long k2 = keys2[m];
  if (k2 != ~0ull) keys[m] = k2;
}

// ---------------- GEMM C: out = embed[idx] * w_out^T (unchanged) ----------------
__global__ __launch_bounds__(256) void k_gemm_out(
    const _Float16* __restrict__ eh, const unsigned long long* __restrict__ keys,
    const _Float16* __restrict__ woh, const float* __restrict__ b_out,
    const float* __restrict__ mask, float* __restrict__ out) {
  __shared__ _Float16 sA[128 * 32], sB[128 * 32];
  __shared__ float sC[32 * 129];
  const int n0 = blockIdx.x * 128, m0 = blockIdx.y * 128;
  const int tid = threadIdx.x, lane = tid & 63, w = tid >> 6;
  const int wr = w >> 1, wc = w & 1, lr = lane & 15, lk = lane >> 4;
  f32x4 acc[4][4] = {};

  const int g0 = w * 128 + lane, g1 = g0 + 64;
  const int rA0 = g0 >> 2, cA0 = g0 & 3, rA1 = g1 >> 2, cA1 = g1 & 3;
  const int lb0 = (w * 128) * 16, lb1 = (w * 128 + 64) * 16;
  const unsigned i0 = (unsigned)(keys[m0 + rA0] & 0xFFFFFFFFull);
  const unsigned i1 = (unsigned)(keys[m0 + rA1] & 0xFFFFFFFFull);
  const _Float16* srcA0 = eh + (size_t)i0 * D + cA0 * 8;
  const _Float16* srcA1 = eh + (size_t)i1 * D + cA1 * 8;

  for (int kt = 0; kt < D / 32; ++kt) {
    const int k0 = kt * 32;
    gload16(srcA0 + k0, (char*)sA + lb0);
    gload16(srcA1 + k0, (char*)sA + lb1);
    gload16(woh + (size_t)(n0 + rA0) * D + k0 + cA0 * 8, (char*)sB + lb0);
    gload16(woh + (size_t)(n0 + rA1) * D + k0 + cA1 * 8, (char*)sB + lb1);
    __syncthreads();
    half8 a[4], b[4];
#pragma unroll
    for (int f = 0; f < 4; ++f) {
      a[f] = *(const half8*)(sA + (wr * 64 + f * 16 + lr) * 32 + lk * 8);
      b[f] = *(const half8*)(sB + (wc * 64 + f * 16 + lr) * 32 + lk * 8);
    }
#pragma unroll
    for (int fm = 0; fm < 4; ++fm)
#pragma unroll
      for (int fn = 0; fn < 4; ++fn)
        acc[fm][fn] = __builtin_amdgcn_mfma_f32_16x16x32_f16(a[fm], b[fn], acc[fm][fn], 0, 0, 0);
    __syncthreads();
  }
  for (int ch = 0; ch < 4; ++ch) {
    __syncthreads();
    if (wr == (ch >> 1)) {
      int fb = (ch & 1) * 2;
#pragma unroll
      for (int f2 = 0; f2 < 2; ++f2) {
        int fm = fb + f2;
#pragma unroll
        for (int fn = 0; fn < 4; ++fn)
#pragma unroll
          for (int j = 0; j < 4; ++j) {
            int lrow = f2 * 16 + lk * 4 + j;
            int col = wc * 64 + fn * 16 + lr;
            sC[lrow * 129 + col] = acc[fm][fn][j] + b_out[n0 + col];
          }
      }
    }
    __syncthreads();
    const int mbase = m0 + ch * 32;
    const int b = mbase >> 11;
    const int l0 = mbase & 2047;
    const float mval = mask[(size_t)b * TLEN + 2 * l0 + lane];
    for (int oo = 0; oo < 32; ++oo) {
      int ocol = w * 32 + oo;
      float v = sC[(lane >> 1) * 129 + ocol];
      out[((size_t)(b * D + n0 + ocol)) * TLEN + 2 * l0 + lane] = v * mval;
    }
  }
}

// ---------------- loss ----------------
__global__ __launch_bounds__(256) void k_loss(const unsigned long long* __restrict__ keys,
                                              const float* __restrict__ t2,
                                              double* __restrict__ acc) {
  int m = blockIdx.x * 256 + threadIdx.x;
  unsigned long long k = keys[m];
  float mval = key_to_f32((unsigned)(k >> 32));
  double c = (double)mval + 1024.0 + (double)t2[m];
#pragma unroll
  for (int mk = 1; mk < 64; mk <<= 1) c += __shfl_xor(c, mk, 64);
  __shared__ double part[4];
  if ((threadIdx.x & 63) == 0) part[threadIdx.x >> 6] = c;
  __syncthreads();
  if (threadIdx.x == 0) atomicAdd(acc, part[0] + part[1] + part[2] + part[3]);
}

__global__ void k_finalize(const double* __restrict__ acc, float* __restrict__ dst) {
  if (threadIdx.x == 0 && blockIdx.x == 0) *dst = (float)(*acc * (1.0 / 16777216.0));
}

// ---------------- host ----------------
extern "C" void kernel_launch(void* const* d_in, const int* in_sizes, int n_in,
                              void* d_out, int out_size, void* d_ws, size_t ws_size,
                              hipStream_t stream) {
  (void)in_sizes; (void)n_in; (void)out_size;
  const float* x      = (const float*)d_in[0];
  const float* xmask  = (const float*)d_in[1];
  const float* w_in   = (const float*)d_in[2];
  const float* b_in   = (const float*)d_in[3];
  const float* embed  = (const float*)d_in[4];
  const float* w_out  = (const float*)d_in[5];
  const float* b_out  = (const float*)d_in[6];
  float* out = (float*)d_out;

  _Float16* xh = (_Float16*)d_out;
  _Float16* xl = xh + (size_t)MTOK * KIN;

  char* p = (char*)d_ws;
  auto take = [&](size_t sz) { char* r = p; p += (sz + 255) & ~(size_t)255; return r; };
  _Float16* wh   = (_Float16*)take((size_t)D * KIN * 2);
  _Float16* wl   = (_Float16*)take((size_t)D * KIN * 2);
  _Float16* eh   = (_Float16*)take((size_t)NCODE * D * 2);
  _Float16* el   = (_Float16*)take((size_t)NCODE * D * 2);
  _Float16* woh  = (_Float16*)take((size_t)D * D * 2);
  float* e2c     = (float*)take((size_t)NCODE * 4);
  _Float16* tokh = (_Float16*)take((size_t)MTOK * D * 2);
  _Float16* tokl = (_Float16*)take((size_t)MTOK * D * 2);
  float* t2      = (float*)take((size_t)MTOK * 4);
  unsigned long long* keys  = (unsigned long long*)take((size_t)MTOK * 8);
  unsigned long long* keys2 = (unsigned long long*)take((size_t)MTOK * 8);
  unsigned long long* skKey = (unsigned long long*)take((size_t)MTOK * 32 * 8);
  float* skSnd   = (float*)take((size_t)MTOK * 32 * 4);
  int* list      = (int*)take((size_t)CAP * 4);
  int* counter   = (int*)take(256);
  double* lossacc = (double*)take(256);
  if ((size_t)(p - (char*)d_ws) > ws_size) return;

  hipMemsetAsync(keys2, 0xFF, (size_t)MTOK * 8, stream);
  hipMemsetAsync(t2, 0, (size_t)MTOK * 4, stream);
  hipMemsetAsync(list, 0, (size_t)CAP * 4, stream);
  hipMemsetAsync(counter, 0, 256, stream);
  hipMemsetAsync(lossacc, 0, 8, stream);

  k_pack_x<<<dim3(64, 32, 8), 256, 0, stream>>>(x, xh, xl);
  k_split<<<(D * KIN + 255) / 256, 256, 0, stream>>>(w_in, wh, wl, D * KIN);
  k_split<<<(NCODE * D + 255) / 256, 256, 0, stream>>>(embed, eh, el, NCODE * D);
  k_tohalf<<<(D * D + 255) / 256, 256, 0, stream>>>(w_out, woh, D * D);
  k_e2<<<NCODE / 4, 256, 0, stream>>>(embed, e2c);

  // tok GEMM: 3-product, M=16384 x N=1024 -> 512 blocks
  k_gemm_tok3<KIN, 3><<<512, 512, 0, stream>>>(xh, xl, wh, wl, b_in, tokh, tokl, t2);

  // score pass-1: hh-only, M=16384 x N=2048 -> 1024 blocks
  k_score1<<<1024, 512, 0, stream>>>(tokh, eh, e2c, skKey, skSnd);
  k_flag<<<MTOK / 256, 256, 0, stream>>>(skKey, skSnd, keys, list, counter);
  // rescore flagged (CAP rows) vs all codes, 3-product
  k_rescore<<<dim3(NCODE / 128, CAP / 128), 256, 0, stream>>>(tokh, tokl, eh, el, e2c, list, keys2);
  k_merge<<<MTOK / 256, 256, 0, stream>>>(keys, keys2);

  k_gemm_out<<<dim3(D / 128, MTOK / 128), 256, 0, stream>>>(eh, keys, woh, b_out, xmask, out);

  k_loss<<<MTOK / 256, 256, 0, stream>>>(keys, t2, lossacc);
  k_finalize<<<1, 64, 0, stream>>>(lossacc, out + (size_t)MTOK * KIN);
}

// Round 7
// 496.409 us; speedup vs baseline: 2.2103x; 2.2103x over previous
//
#include <hip/hip_runtime.h>

typedef _Float16 half8 __attribute__((ext_vector_type(8)));
typedef float f32x4 __attribute__((ext_vector_type(4)));

static constexpr int D = 1024;       // VQ_C == C_IN
static constexpr int NCODE = 2048;   // codebook size
static constexpr int MTOK = 16384;   // B * L = 8 * 2048
static constexpr int KIN = 2048;     // C_IN * DS
static constexpr int TLEN = 4096;
static constexpr int CAP = 2048;     // max rescored tokens (est. ~345 flagged)
#define TAU 0.4f

__device__ __forceinline__ void gload16(const void* g, void* l) {
  __builtin_amdgcn_global_load_lds(
      (const __attribute__((address_space(1))) void*)g,
      (__attribute__((address_space(3))) void*)l, 16, 0, 0);
}

#define SBAR()   asm volatile("s_barrier" ::: "memory")
#define WAITV6() asm volatile("s_waitcnt vmcnt(6)" ::: "memory")
#define WAITV4() asm volatile("s_waitcnt vmcnt(4)" ::: "memory")
#define WAITV3() asm volatile("s_waitcnt vmcnt(3)" ::: "memory")
#define WAITV0() asm volatile("s_waitcnt vmcnt(0)" ::: "memory")

__device__ __forceinline__ float key_to_f32(unsigned u) {
  unsigned bits = (u & 0x80000000u) ? (u & 0x7FFFFFFFu) : ~u;
  return __uint_as_float(bits);
}
__device__ __forceinline__ unsigned f32_to_key(float f) {
  unsigned ub = __float_as_uint(f);
  return (ub & 0x80000000u) ? ~ub : (ub | 0x80000000u);
}

// ---------------- pack kernels (unchanged) ----------------
__global__ __launch_bounds__(256) void k_pack_x(const float* __restrict__ x,
                                                _Float16* __restrict__ xh,
                                                _Float16* __restrict__ xl) {
  __shared__ float lds[32][65];
  const int tt0 = blockIdx.x * 64;
  const int cc0 = blockIdx.y * 32;
  const int b = blockIdx.z;
  const float* xb = x + ((size_t)b * D + cc0) * TLEN + tt0;
#pragma unroll
  for (int i = 0; i < 8; ++i) {
    int idx = threadIdx.x + i * 256;
    lds[idx >> 6][idx & 63] = xb[(size_t)(idx >> 6) * TLEN + (idx & 63)];
  }
  __syncthreads();
  const size_t mrow0 = (size_t)b * 2048 + (tt0 >> 1);
#pragma unroll
  for (int i = 0; i < 8; ++i) {
    int idx = threadIdx.x + i * 256;
    int r = idx >> 6, kk = idx & 63;
    float v = lds[kk >> 1][2 * r + (kk & 1)];
    _Float16 h = (_Float16)v;
    size_t off = (mrow0 + r) * (size_t)KIN + (size_t)cc0 * 2 + kk;
    xh[off] = h;
    xl[off] = (_Float16)(v - (float)h);
  }
}

__global__ __launch_bounds__(256) void k_split(const float* __restrict__ s,
                                               _Float16* __restrict__ hi,
                                               _Float16* __restrict__ lo, int n) {
  int i = blockIdx.x * 256 + threadIdx.x;
  if (i < n) {
    float v = s[i];
    _Float16 h = (_Float16)v;
    hi[i] = h;
    lo[i] = (_Float16)(v - (float)h);
  }
}

__global__ __launch_bounds__(256) void k_tohalf(const float* __restrict__ s,
                                                _Float16* __restrict__ hi, int n) {
  int i = blockIdx.x * 256 + threadIdx.x;
  if (i < n) hi[i] = (_Float16)s[i];
}

__global__ __launch_bounds__(256) void k_e2(const float* __restrict__ embed,
                                            float* __restrict__ e2c) {
  int row = blockIdx.x * 4 + (threadIdx.x >> 6);
  int lane = threadIdx.x & 63;
  const float* er = embed + (size_t)row * D;
  double s = 0.0;
  for (int i = lane; i < D; i += 64) { double v = er[i]; s += v * v; }
#pragma unroll
  for (int mk = 1; mk < 64; mk <<= 1) s += __shfl_xor(s, mk, 64);
  if (lane == 0) e2c[row] = (float)(s - 1024.0);
}

// ---------------- tok GEMM: 3-product split (R4 structure, unchanged) ----------------
template <int KDIM, int LOG_GX>
__global__ __launch_bounds__(512, 2) void k_gemm_tok3(
    const _Float16* __restrict__ Ah_, const _Float16* __restrict__ Al_,
    const _Float16* __restrict__ Bh_, const _Float16* __restrict__ Bl_,
    const float* __restrict__ vec,
    _Float16* __restrict__ outh, _Float16* __restrict__ outl,
    float* __restrict__ t2) {
  __shared__ _Float16 lds[3 * 24576];
  const int nwg = gridDim.x;
  const int bid = blockIdx.x;
  const int q = nwg >> 3;
  const int b2 = (bid & 7) * q + (bid >> 3);
  const int n0 = (b2 & ((1 << LOG_GX) - 1)) * 128;
  const int m0 = (b2 >> LOG_GX) * 256;

  const int tid = threadIdx.x, lane = tid & 63, w = tid >> 6;
  const int wr = w >> 1, wc = w & 1, lr = lane & 15, lk = lane >> 4;
  constexpr int NT = KDIM / 32;

  const int cswz8 = (((lane & 3) ^ ((lane >> 3) & 3))) * 8;
  const int rswz8 = (lk ^ ((lr >> 1) & 3)) * 8;

  f32x4 acc[4][4] = {};
  half8 ahA[4], bhA[4], ahB[4], bhB[4], al[4], bl[4];

  auto stageA2 = [&](const _Float16* __restrict__ src, int k0, char* regionBase) {
    int slot0 = w * 64 + lane;
    gload16(src + (size_t)(m0 + (slot0 >> 2)) * KDIM + k0 + cswz8,
            regionBase + w * 1024);
    int slot1 = slot0 + 512;
    gload16(src + (size_t)(m0 + (slot1 >> 2)) * KDIM + k0 + cswz8,
            regionBase + w * 1024 + 8192);
  };
  auto stageB2 = [&](int k0, char* stageBase) {
    int slot = w * 64 + lane;
    size_t go = (size_t)(n0 + (slot >> 2)) * KDIM + k0 + cswz8;
    gload16(Bh_ + go, stageBase + 32768 + w * 1024);
    gload16(Bl_ + go, stageBase + 40960 + w * 1024);
  };
  auto stageAll = [&](int t, int c) {
    char* sb = (char*)lds + c * 49152;
    stageA2(Ah_, t * 32, sb);
    stageA2(Al_, t * 32, sb + 16384);
    stageB2(t * 32, sb);
  };

  int c0 = 0, c1 = 1, c2 = 2;
  stageAll(0, 0);
  stageAll(1, 1);
  WAITV6();
  SBAR();
#pragma unroll
  for (int f = 0; f < 4; ++f) {
    ahA[f] = *(const half8*)(lds + (wr * 64 + f * 16 + lr) * 32 + rswz8);
    bhA[f] = *(const half8*)(lds + 16384 + (wc * 64 + f * 16 + lr) * 32 + rswz8);
  }

  auto tile_body = [&](int t, half8 (&ahC)[4], half8 (&bhC)[4],
                       half8 (&ahN)[4], half8 (&bhN)[4]) {
    const _Float16* sb = lds + c0 * 24576;
    char* dstb = (char*)lds + c2 * 49152;
    const bool st = (t + 2) < NT;
    const int ks = (t + 2) * 32;

#pragma unroll
    for (int f = 0; f < 4; ++f)
      bl[f] = *(const half8*)(sb + 20480 + (wc * 64 + f * 16 + lr) * 32 + rswz8);
    if (st) stageA2(Ah_, ks, dstb);
    SBAR();
    __builtin_amdgcn_s_setprio(1);
#pragma unroll
    for (int fm = 0; fm < 4; ++fm)
#pragma unroll
      for (int fn = 0; fn < 4; ++fn)
        acc[fm][fn] = __builtin_amdgcn_mfma_f32_16x16x32_f16(ahC[fm], bhC[fn], acc[fm][fn], 0, 0, 0);
    __builtin_amdgcn_s_setprio(0);
    SBAR();

#pragma unroll
    for (int f = 0; f < 4; ++f)
      al[f] = *(const half8*)(sb + 8192 + (wr * 64 + f * 16 + lr) * 32 + rswz8);
    if (st) stageA2(Al_, ks, dstb + 16384);
    WAITV4();
    SBAR();
    __builtin_amdgcn_s_setprio(1);
#pragma unroll
    for (int fm = 0; fm < 4; ++fm)
#pragma unroll
      for (int fn = 0; fn < 4; ++fn)
        acc[fm][fn] = __builtin_amdgcn_mfma_f32_16x16x32_f16(ahC[fm], bl[fn], acc[fm][fn], 0, 0, 0);
    __builtin_amdgcn_s_setprio(0);
    SBAR();

    if (t + 1 < NT) {
      const _Float16* sb1 = lds + c1 * 24576;
#pragma unroll
      for (int f = 0; f < 4; ++f) {
        ahN[f] = *(const half8*)(sb1 + (wr * 64 + f * 16 + lr) * 32 + rswz8);
        bhN[f] = *(const half8*)(sb1 + 16384 + (wc * 64 + f * 16 + lr) * 32 + rswz8);
      }
    }
    if (st) stageB2(ks, dstb);
    SBAR();
    __builtin_amdgcn_s_setprio(1);
#pragma unroll
    for (int fm = 0; fm < 4; ++fm)
#pragma unroll
      for (int fn = 0; fn < 4; ++fn)
        acc[fm][fn] = __builtin_amdgcn_mfma_f32_16x16x32_f16(al[fm], bhC[fn], acc[fm][fn], 0, 0, 0);
    __builtin_amdgcn_s_setprio(0);
    if (st) { WAITV6(); } else if (t + 1 < NT) { WAITV0(); }
    SBAR();

    int tmp = c0; c0 = c1; c1 = c2; c2 = tmp;
  };

  for (int tt = 0; tt < NT; tt += 2) {
    tile_body(tt,     ahA, bhA, ahB, bhB);
    tile_body(tt + 1, ahB, bhB, ahA, bhA);
  }

  // epilogue: +b_in, split to f16 hi/lo, accumulate ||t||^2 per token row
#pragma unroll
  for (int fm = 0; fm < 4; ++fm) {
#pragma unroll
    for (int j = 0; j < 4; ++j) {
      int row = wr * 64 + fm * 16 + lk * 4 + j;
      size_t m = (size_t)m0 + row;
      float v2 = 0.f;
#pragma unroll
      for (int fn = 0; fn < 4; ++fn) {
        int col = n0 + wc * 64 + fn * 16 + lr;
        float v = acc[fm][fn][j] + vec[col];
        v2 += v * v;
        _Float16 h = (_Float16)v;
        outh[m * D + col] = h;
        outl[m * D + col] = (_Float16)(v - (float)h);
      }
#pragma unroll
      for (int mk = 1; mk < 16; mk <<= 1) v2 += __shfl_xor(v2, mk, 64);
      if (lr == 0) atomicAdd(&t2[m], v2);
    }
  }
}

// ---------------- score pass-1: single hh product + top-2 margin ----------------
// 256x128 tile, 512 thr, hi-only staging; per-WAVE result slot [m*32 + nb*2 + wc].
__global__ __launch_bounds__(512, 4) void k_score1(
    const _Float16* __restrict__ Ah_, const _Float16* __restrict__ Bh_,
    const float* __restrict__ e2c,
    unsigned long long* __restrict__ skKey, float* __restrict__ skSnd) {
  __shared__ _Float16 lds[3 * 12288];  // per buf: A[256x32] 16KB @0, B[128x32] 8KB @16384B
  const int nwg = gridDim.x, bid = blockIdx.x, q = nwg >> 3;
  const int b2 = (bid & 7) * q + (bid >> 3);
  const int nb = b2 & 15;
  const int n0 = nb * 128, m0 = (b2 >> 4) * 256;
  const int tid = threadIdx.x, lane = tid & 63, w = tid >> 6;
  const int wr = w >> 1, wc = w & 1, lr = lane & 15, lk = lane >> 4;
  constexpr int NT = D / 32;
  const int cswz8 = (((lane & 3) ^ ((lane >> 3) & 3))) * 8;
  const int rswz8 = (lk ^ ((lr >> 1) & 3)) * 8;

  f32x4 acc[4][4] = {};

  auto stage = [&](int t, int c) {  // 3 loads/thread
    char* sb = (char*)lds + c * 24576;
    const int k0 = t * 32;
    int slot0 = w * 64 + lane;
    gload16(Ah_ + (size_t)(m0 + (slot0 >> 2)) * D + k0 + cswz8, sb + w * 1024);
    int slot1 = slot0 + 512;
    gload16(Ah_ + (size_t)(m0 + (slot1 >> 2)) * D + k0 + cswz8, sb + w * 1024 + 8192);
    gload16(Bh_ + (size_t)(n0 + (slot0 >> 2)) * D + k0 + cswz8, sb + 16384 + w * 1024);
  };

  stage(0, 0);
  stage(1, 1);
  WAITV3();
  SBAR();

  int c0 = 0, c1 = 1, c2 = 2;
  for (int t = 0; t < NT; ++t) {
    const _Float16* sb = lds + c0 * 12288;
    half8 ah[4], bh[4];
#pragma unroll
    for (int f = 0; f < 4; ++f) {
      ah[f] = *(const half8*)(sb + (wr * 64 + f * 16 + lr) * 32 + rswz8);
      bh[f] = *(const half8*)(sb + 8192 + (wc * 64 + f * 16 + lr) * 32 + rswz8);
    }
    const bool st = (t + 2) < NT;
    if (st) stage(t + 2, c2);
    SBAR();
    __builtin_amdgcn_s_setprio(1);
#pragma unroll
    for (int fm = 0; fm < 4; ++fm)
#pragma unroll
      for (int fn = 0; fn < 4; ++fn)
        acc[fm][fn] = __builtin_amdgcn_mfma_f32_16x16x32_f16(ah[fm], bh[fn], acc[fm][fn], 0, 0, 0);
    __builtin_amdgcn_s_setprio(0);
    if (st) { WAITV3(); } else if (t + 1 < NT) { WAITV0(); }
    SBAR();
    int tmp = c0; c0 = c1; c1 = c2; c2 = tmp;
  }

  // epilogue: per row: top-2 of mval over THIS WAVE's 64 codes -> private slot
#pragma unroll
  for (int fm = 0; fm < 4; ++fm) {
#pragma unroll
    for (int j = 0; j < 4; ++j) {
      int row = wr * 64 + fm * 16 + lk * 4 + j;
      size_t m = (size_t)m0 + row;
      float b1 = 3.4e38f, bb2 = 3.4e38f;
      int i1 = 0x7FFFFFFF;
#pragma unroll
      for (int fn = 0; fn < 4; ++fn) {
        int col = n0 + wc * 64 + fn * 16 + lr;
        float mv = e2c[col] - 2.0f * acc[fm][fn][j];
        if (mv < b1) { bb2 = b1; b1 = mv; i1 = col; }
        else if (mv < bb2) { bb2 = mv; }
      }
#pragma unroll
      for (int mk = 1; mk < 16; mk <<= 1) {
        float ob1 = __shfl_xor(b1, mk, 64);
        float ob2 = __shfl_xor(bb2, mk, 64);
        int oi = __shfl_xor(i1, mk, 64);
        if (ob1 < b1) { bb2 = fminf(b1, ob2); b1 = ob1; i1 = oi; }
        else { bb2 = fminf(bb2, ob1); }
      }
      if (lr == 0) {
        unsigned long long key = ((unsigned long long)f32_to_key(b1) << 32) | (unsigned)i1;
        skKey[m * 32 + nb * 2 + wc] = key;
        skSnd[m * 32 + nb * 2 + wc] = bb2;
      }
    }
  }
}

// ---------------- flag: global top-2 over 32 slots, margin test, compact ----------------
__global__ __launch_bounds__(256) void k_flag(const unsigned long long* __restrict__ skKey,
                                              const float* __restrict__ skSnd,
                                              unsigned long long* __restrict__ keys,
                                              int* __restrict__ list, int* __restrict__ counter) {
  int m = blockIdx.x * 256 + threadIdx.x;
  unsigned long long best = ~0ull;
  int bsl = 0;
#pragma unroll
  for (int sl = 0; sl < 32; ++sl) {
    unsigned long long k = skKey[(size_t)m * 32 + sl];
    if (k < best) { best = k; bsl = sl; }
  }
  float b1 = key_to_f32((unsigned)(best >> 32));
  float second = skSnd[(size_t)m * 32 + bsl];
#pragma unroll
  for (int sl = 0; sl < 32; ++sl) {
    if (sl != bsl) second = fminf(second, key_to_f32((unsigned)(skKey[(size_t)m * 32 + sl] >> 32)));
  }
  keys[m] = best;
  if (second - b1 < TAU) {
    int p = atomicAdd(counter, 1);
    if (p < CAP) list[p] = m;
  }
}

// ---------------- rescore: 3-product exact scoring of flagged tokens ----------------
// R7: count-guarded. Blocks beyond the flagged count exit immediately; padded
// rows never issue atomics (R6's 659us was ~54k atomicMins to keys2[0] from
// the zero-padded list — single-address device-scope contention across XCDs).
__global__ __launch_bounds__(256) void k_rescore(
    const _Float16* __restrict__ tokh, const _Float16* __restrict__ tokl,
    const _Float16* __restrict__ eh, const _Float16* __restrict__ el,
    const float* __restrict__ e2c, const int* __restrict__ list,
    const int* __restrict__ counter,
    unsigned long long* __restrict__ keys2) {
  const int count = min(counter[0], CAP);
  const int m0 = blockIdx.y * 128;
  if (m0 >= count) return;
  __shared__ _Float16 sAh[128 * 32], sAl[128 * 32], sBh[128 * 32], sBl[128 * 32];
  const int n0 = blockIdx.x * 128;
  const int tid = threadIdx.x, lane = tid & 63, w = tid >> 6;
  const int wr = w >> 1, wc = w & 1, lr = lane & 15, lk = lane >> 4;
  f32x4 acc[4][4] = {};

  const int g0 = w * 128 + lane, g1 = g0 + 64;
  const int rA0 = g0 >> 2, cA0 = g0 & 3, rA1 = g1 >> 2, cA1 = g1 & 3;
  const int lb0 = (w * 128) * 16, lb1 = (w * 128 + 64) * 16;
  const int tk0 = list[m0 + rA0], tk1 = list[m0 + rA1];

  for (int kt = 0; kt < D / 32; ++kt) {
    const int k0 = kt * 32;
    gload16(tokh + (size_t)tk0 * D + k0 + cA0 * 8, (char*)sAh + lb0);
    gload16(tokh + (size_t)tk1 * D + k0 + cA1 * 8, (char*)sAh + lb1);
    gload16(tokl + (size_t)tk0 * D + k0 + cA0 * 8, (char*)sAl + lb0);
    gload16(tokl + (size_t)tk1 * D + k0 + cA1 * 8, (char*)sAl + lb1);
    gload16(eh + (size_t)(n0 + rA0) * D + k0 + cA0 * 8, (char*)sBh + lb0);
    gload16(eh + (size_t)(n0 + rA1) * D + k0 + cA1 * 8, (char*)sBh + lb1);
    gload16(el + (size_t)(n0 + rA0) * D + k0 + cA0 * 8, (char*)sBl + lb0);
    gload16(el + (size_t)(n0 + rA1) * D + k0 + cA1 * 8, (char*)sBl + lb1);
    __syncthreads();
    half8 ah[4], al2[4], bh[4], bl2[4];
#pragma unroll
    for (int f = 0; f < 4; ++f) {
      ah[f]  = *(const half8*)(sAh + (wr * 64 + f * 16 + lr) * 32 + lk * 8);
      al2[f] = *(const half8*)(sAl + (wr * 64 + f * 16 + lr) * 32 + lk * 8);
      bh[f]  = *(const half8*)(sBh + (wc * 64 + f * 16 + lr) * 32 + lk * 8);
      bl2[f] = *(const half8*)(sBl + (wc * 64 + f * 16 + lr) * 32 + lk * 8);
    }
#pragma unroll
    for (int fm = 0; fm < 4; ++fm)
#pragma unroll
      for (int fn = 0; fn < 4; ++fn) {
        acc[fm][fn] = __builtin_amdgcn_mfma_f32_16x16x32_f16(ah[fm], bh[fn], acc[fm][fn], 0, 0, 0);
        acc[fm][fn] = __builtin_amdgcn_mfma_f32_16x16x32_f16(ah[fm], bl2[fn], acc[fm][fn], 0, 0, 0);
        acc[fm][fn] = __builtin_amdgcn_mfma_f32_16x16x32_f16(al2[fm], bh[fn], acc[fm][fn], 0, 0, 0);
      }
    __syncthreads();
  }
#pragma unroll
  for (int fm = 0; fm < 4; ++fm) {
#pragma unroll
    for (int j = 0; j < 4; ++j) {
      int row = wr * 64 + fm * 16 + lk * 4 + j;
      if (m0 + row >= count) continue;
      int tm = list[m0 + row];
      float best = 3.4e38f;
      int bidx = 0x7FFFFFFF;
#pragma unroll
      for (int fn = 0; fn < 4; ++fn) {
        int col = n0 + wc * 64 + fn * 16 + lr;
        float mv = e2c[col] - 2.0f * acc[fm][fn][j];
        if (mv < best) { best = mv; bidx = col; }
      }
#pragma unroll
      for (int mk = 1; mk < 16; mk <<= 1) {
        float ob = __shfl_xor(best, mk, 64);
        int oi = __shfl_xor(bidx, mk, 64);
        if (ob < best || (ob == best && oi < bidx)) { best = ob; bidx = oi; }
      }
      if (lr == 0) {
        unsigned long long key = ((unsigned long long)f32_to_key(best) << 32) | (unsigned)bidx;
        atomicMin(&keys2[tm], key);
      }
    }
  }
}

__global__ __launch_bounds__(256) void k_merge(unsigned long long* __restrict__ keys,
                                               const unsigned long long* __restrict__ keys2) {
  int m = blockIdx.x * 256 + threadIdx.x;
  unsigned long long k2 = keys2[m];
  if (k2 != ~0ull) keys[m] = k2;
}

// ---------------- GEMM C: out = embed[idx] * w_out^T (unchanged) ----------------
__global__ __launch_bounds__(256) void k_gemm_out(
    const _Float16* __restrict__ eh, const unsigned long long* __restrict__ keys,
    const _Float16* __restrict__ woh, const float* __restrict__ b_out,
    const float* __restrict__ mask, float* __restrict__ out) {
  __shared__ _Float16 sA[128 * 32], sB[128 * 32];
  __shared__ float sC[32 * 129];
  const int n0 = blockIdx.x * 128, m0 = blockIdx.y * 128;
  const int tid = threadIdx.x, lane = tid & 63, w = tid >> 6;
  const int wr = w >> 1, wc = w & 1, lr = lane & 15, lk = lane >> 4;
  f32x4 acc[4][4] = {};

  const int g0 = w * 128 + lane, g1 = g0 + 64;
  const int rA0 = g0 >> 2, cA0 = g0 & 3, rA1 = g1 >> 2, cA1 = g1 & 3;
  const int lb0 = (w * 128) * 16, lb1 = (w * 128 + 64) * 16;
  const unsigned i0 = (unsigned)(keys[m0 + rA0] & 0xFFFFFFFFull);
  const unsigned i1 = (unsigned)(keys[m0 + rA1] & 0xFFFFFFFFull);
  const _Float16* srcA0 = eh + (size_t)i0 * D + cA0 * 8;
  const _Float16* srcA1 = eh + (size_t)i1 * D + cA1 * 8;

  for (int kt = 0; kt < D / 32; ++kt) {
    const int k0 = kt * 32;
    gload16(srcA0 + k0, (char*)sA + lb0);
    gload16(srcA1 + k0, (char*)sA + lb1);
    gload16(woh + (size_t)(n0 + rA0) * D + k0 + cA0 * 8, (char*)sB + lb0);
    gload16(woh + (size_t)(n0 + rA1) * D + k0 + cA1 * 8, (char*)sB + lb1);
    __syncthreads();
    half8 a[4], b[4];
#pragma unroll
    for (int f = 0; f < 4; ++f) {
      a[f] = *(const half8*)(sA + (wr * 64 + f * 16 + lr) * 32 + lk * 8);
      b[f] = *(const half8*)(sB + (wc * 64 + f * 16 + lr) * 32 + lk * 8);
    }
#pragma unroll
    for (int fm = 0; fm < 4; ++fm)
#pragma unroll
      for (int fn = 0; fn < 4; ++fn)
        acc[fm][fn] = __builtin_amdgcn_mfma_f32_16x16x32_f16(a[fm], b[fn], acc[fm][fn], 0, 0, 0);
    __syncthreads();
  }
  for (int ch = 0; ch < 4; ++ch) {
    __syncthreads();
    if (wr == (ch >> 1)) {
      int fb = (ch & 1) * 2;
#pragma unroll
      for (int f2 = 0; f2 < 2; ++f2) {
        int fm = fb + f2;
#pragma unroll
        for (int fn = 0; fn < 4; ++fn)
#pragma unroll
          for (int j = 0; j < 4; ++j) {
            int lrow = f2 * 16 + lk * 4 + j;
            int col = wc * 64 + fn * 16 + lr;
            sC[lrow * 129 + col] = acc[fm][fn][j] + b_out[n0 + col];
          }
      }
    }
    __syncthreads();
    const int mbase = m0 + ch * 32;
    const int b = mbase >> 11;
    const int l0 = mbase & 2047;
    const float mval = mask[(size_t)b * TLEN + 2 * l0 + lane];
    for (int oo = 0; oo < 32; ++oo) {
      int ocol = w * 32 + oo;
      float v = sC[(lane >> 1) * 129 + ocol];
      out[((size_t)(b * D + n0 + ocol)) * TLEN + 2 * l0 + lane] = v * mval;
    }
  }
}

// ---------------- loss ----------------
__global__ __launch_bounds__(256) void k_loss(const unsigned long long* __restrict__ keys,
                                              const float* __restrict__ t2,
                                              double* __restrict__ acc) {
  int m = blockIdx.x * 256 + threadIdx.x;
  unsigned long long k = keys[m];
  float mval = key_to_f32((unsigned)(k >> 32));
  double c = (double)mval + 1024.0 + (double)t2[m];
#pragma unroll
  for (int mk = 1; mk < 64; mk <<= 1) c += __shfl_xor(c, mk, 64);
  __shared__ double part[4];
  if ((threadIdx.x & 63) == 0) part[threadIdx.x >> 6] = c;
  __syncthreads();
  if (threadIdx.x == 0) atomicAdd(acc, part[0] + part[1] + part[2] + part[3]);
}

__global__ void k_finalize(const double* __restrict__ acc, float* __restrict__ dst) {
  if (threadIdx.x == 0 && blockIdx.x == 0) *dst = (float)(*acc * (1.0 / 16777216.0));
}

// ---------------- host ----------------
extern "C" void kernel_launch(void* const* d_in, const int* in_sizes, int n_in,
                              void* d_out, int out_size, void* d_ws, size_t ws_size,
                              hipStream_t stream) {
  (void)in_sizes; (void)n_in; (void)out_size;
  const float* x      = (const float*)d_in[0];
  const float* xmask  = (const float*)d_in[1];
  const float* w_in   = (const float*)d_in[2];
  const float* b_in   = (const float*)d_in[3];
  const float* embed  = (const float*)d_in[4];
  const float* w_out  = (const float*)d_in[5];
  const float* b_out  = (const float*)d_in[6];
  float* out = (float*)d_out;

  _Float16* xh = (_Float16*)d_out;
  _Float16* xl = xh + (size_t)MTOK * KIN;

  char* p = (char*)d_ws;
  auto take = [&](size_t sz) { char* r = p; p += (sz + 255) & ~(size_t)255; return r; };
  _Float16* wh   = (_Float16*)take((size_t)D * KIN * 2);
  _Float16* wl   = (_Float16*)take((size_t)D * KIN * 2);
  _Float16* eh   = (_Float16*)take((size_t)NCODE * D * 2);
  _Float16* el   = (_Float16*)take((size_t)NCODE * D * 2);
  _Float16* woh  = (_Float16*)take((size_t)D * D * 2);
  float* e2c     = (float*)take((size_t)NCODE * 4);
  _Float16* tokh = (_Float16*)take((size_t)MTOK * D * 2);
  _Float16* tokl = (_Float16*)take((size_t)MTOK * D * 2);
  float* t2      = (float*)take((size_t)MTOK * 4);
  unsigned long long* keys  = (unsigned long long*)take((size_t)MTOK * 8);
  unsigned long long* keys2 = (unsigned long long*)take((size_t)MTOK * 8);
  unsigned long long* skKey = (unsigned long long*)take((size_t)MTOK * 32 * 8);
  float* skSnd   = (float*)take((size_t)MTOK * 32 * 4);
  int* list      = (int*)take((size_t)CAP * 4);
  int* counter   = (int*)take(256);
  double* lossacc = (double*)take(256);
  if ((size_t)(p - (char*)d_ws) > ws_size) return;

  hipMemsetAsync(keys2, 0xFF, (size_t)MTOK * 8, stream);
  hipMemsetAsync(t2, 0, (size_t)MTOK * 4, stream);
  hipMemsetAsync(list, 0, (size_t)CAP * 4, stream);
  hipMemsetAsync(counter, 0, 256, stream);
  hipMemsetAsync(lossacc, 0, 8, stream);

  k_pack_x<<<dim3(64, 32, 8), 256, 0, stream>>>(x, xh, xl);
  k_split<<<(D * KIN + 255) / 256, 256, 0, stream>>>(w_in, wh, wl, D * KIN);
  k_split<<<(NCODE * D + 255) / 256, 256, 0, stream>>>(embed, eh, el, NCODE * D);
  k_tohalf<<<(D * D + 255) / 256, 256, 0, stream>>>(w_out, woh, D * D);
  k_e2<<<NCODE / 4, 256, 0, stream>>>(embed, e2c);

  // tok GEMM: 3-product, M=16384 x N=1024 -> 512 blocks
  k_gemm_tok3<KIN, 3><<<512, 512, 0, stream>>>(xh, xl, wh, wl, b_in, tokh, tokl, t2);

  // score pass-1: hh-only, M=16384 x N=2048 -> 1024 blocks
  k_score1<<<1024, 512, 0, stream>>>(tokh, eh, e2c, skKey, skSnd);
  k_flag<<<MTOK / 256, 256, 0, stream>>>(skKey, skSnd, keys, list, counter);
  // rescore flagged (count-guarded; grid sized for CAP, idle blocks exit)
  k_rescore<<<dim3(NCODE / 128, CAP / 128), 256, 0, stream>>>(tokh, tokl, eh, el, e2c, list, counter, keys2);
  k_merge<<<MTOK / 256, 256, 0, stream>>>(keys, keys2);

  k_gemm_out<<<dim3(D / 128, MTOK / 128), 256, 0, stream>>>(eh, keys, woh, b_out, xmask, out);

  k_loss<<<MTOK / 256, 256, 0, stream>>>(keys, t2, lossacc);
  k_finalize<<<1, 64, 0, stream>>>(lossacc, out + (size_t)MTOK * KIN);
}

// Round 8
// 452.165 us; speedup vs baseline: 2.4265x; 1.0978x over previous
//
#include <hip/hip_runtime.h>

typedef _Float16 half8 __attribute__((ext_vector_type(8)));
typedef float f32x4 __attribute__((ext_vector_type(4)));

static constexpr int D = 1024;       // VQ_C == C_IN
static constexpr int NCODE = 2048;   // codebook size
static constexpr int MTOK = 16384;   // B * L = 8 * 2048
static constexpr int KIN = 2048;     // C_IN * DS
static constexpr int TLEN = 4096;
static constexpr int CAP = 2048;     // max rescored tokens (est. ~250 flagged)
#define TAU 0.4f

__device__ __forceinline__ void gload16(const void* g, void* l) {
  __builtin_amdgcn_global_load_lds(
      (const __attribute__((address_space(1))) void*)g,
      (__attribute__((address_space(3))) void*)l, 16, 0, 0);
}

#define SBAR()   asm volatile("s_barrier" ::: "memory")
#define WAITV4() asm volatile("s_waitcnt vmcnt(4)" ::: "memory")
#define WAITV0() asm volatile("s_waitcnt vmcnt(0)" ::: "memory")

__device__ __forceinline__ float key_to_f32(unsigned u) {
  unsigned bits = (u & 0x80000000u) ? (u & 0x7FFFFFFFu) : ~u;
  return __uint_as_float(bits);
}
__device__ __forceinline__ unsigned f32_to_key(float f) {
  unsigned ub = __float_as_uint(f);
  return (ub & 0x80000000u) ? ~ub : (ub | 0x80000000u);
}

// ---------------- pack kernels ----------------
__global__ __launch_bounds__(256) void k_pack_x(const float* __restrict__ x,
                                                _Float16* __restrict__ xh,
                                                _Float16* __restrict__ xl) {
  __shared__ float lds[32][65];
  const int tt0 = blockIdx.x * 64;
  const int cc0 = blockIdx.y * 32;
  const int b = blockIdx.z;
  const float* xb = x + ((size_t)b * D + cc0) * TLEN + tt0;
#pragma unroll
  for (int i = 0; i < 8; ++i) {
    int idx = threadIdx.x + i * 256;
    lds[idx >> 6][idx & 63] = xb[(size_t)(idx >> 6) * TLEN + (idx & 63)];
  }
  __syncthreads();
  const size_t mrow0 = (size_t)b * 2048 + (tt0 >> 1);
#pragma unroll
  for (int i = 0; i < 8; ++i) {
    int idx = threadIdx.x + i * 256;
    int r = idx >> 6, kk = idx & 63;
    float v = lds[kk >> 1][2 * r + (kk & 1)];
    _Float16 h = (_Float16)v;
    size_t off = (mrow0 + r) * (size_t)KIN + (size_t)cc0 * 2 + kk;
    xh[off] = h;
    xl[off] = (_Float16)(v - (float)h);
  }
}

__global__ __launch_bounds__(256) void k_split(const float* __restrict__ s,
                                               _Float16* __restrict__ hi,
                                               _Float16* __restrict__ lo, int n) {
  int i = blockIdx.x * 256 + threadIdx.x;
  if (i < n) {
    float v = s[i];
    _Float16 h = (_Float16)v;
    hi[i] = h;
    lo[i] = (_Float16)(v - (float)h);
  }
}

__global__ __launch_bounds__(256) void k_tohalf(const float* __restrict__ s,
                                                _Float16* __restrict__ hi, int n) {
  int i = blockIdx.x * 256 + threadIdx.x;
  if (i < n) hi[i] = (_Float16)s[i];
}

__global__ __launch_bounds__(256) void k_e2(const float* __restrict__ embed,
                                            float* __restrict__ e2c) {
  int row = blockIdx.x * 4 + (threadIdx.x >> 6);
  int lane = threadIdx.x & 63;
  const float* er = embed + (size_t)row * D;
  double s = 0.0;
  for (int i = lane; i < D; i += 64) { double v = er[i]; s += v * v; }
#pragma unroll
  for (int mk = 1; mk < 64; mk <<= 1) s += __shfl_xor(s, mk, 64);
  if (lane == 0) e2c[row] = (float)(s - 1024.0);
}

// ---------------- hh GEMM: 256x256 tile, 8 waves (2x4), 8x4 frags/wave ----------------
// LDS/buf = 32KB (A[256x32] @0, B[256x32] @+16KB), 3 buffers, single barrier/K-tile,
// counted vmcnt(4), T2 chunk-XOR swizzle (write: lane-const pre-swizzled source chunk;
// read: lane-const XOR), setprio around the 32-MFMA cluster.
// MODE 0: tok epilogue (bias, f16 hi store, ||t||^2).  MODE 1: score top-2 slots.
template <int KDIM, int LOG_GX, int MODE>
__global__ __launch_bounds__(512, 2) void k_gemm_hh(
    const _Float16* __restrict__ Ah_, const _Float16* __restrict__ Bh_,
    const float* __restrict__ vec,
    _Float16* __restrict__ outh, float* __restrict__ t2,
    unsigned long long* __restrict__ skKey, float* __restrict__ skSnd) {
  __shared__ _Float16 lds[3 * 16384];  // 3 x 32KB
  const int nwg = gridDim.x, bid = blockIdx.x, q = nwg >> 3;
  const int b2 = (bid & 7) * q + (bid >> 3);
  const int nb = b2 & ((1 << LOG_GX) - 1);
  const int n0 = nb * 256, m0 = (b2 >> LOG_GX) * 256;
  const int tid = threadIdx.x, lane = tid & 63, w = tid >> 6;
  const int wr = w >> 2, wc = w & 3, lr = lane & 15, lk = lane >> 4;
  constexpr int NT = KDIM / 32;
  const int cswz8 = (((lane & 3) ^ ((lane >> 3) & 3))) * 8;  // global-side chunk swizzle
  const int rswz8 = (lk ^ ((lr >> 1) & 3)) * 8;              // read-side chunk swizzle

  f32x4 acc[8][4] = {};

  auto stage = [&](int t, int c) {  // 4 loads/thread = 32KB/block
    char* sb = (char*)(lds + c * 16384);
    const int k0 = t * 32;
    const int r0 = (w * 64 + lane) >> 2;   // 0..127
    gload16(Ah_ + (size_t)(m0 + r0) * KDIM + k0 + cswz8, sb + w * 1024);
    gload16(Ah_ + (size_t)(m0 + 128 + r0) * KDIM + k0 + cswz8, sb + w * 1024 + 8192);
    gload16(Bh_ + (size_t)(n0 + r0) * KDIM + k0 + cswz8, sb + 16384 + w * 1024);
    gload16(Bh_ + (size_t)(n0 + 128 + r0) * KDIM + k0 + cswz8, sb + 16384 + w * 1024 + 8192);
  };

  stage(0, 0);
  stage(1, 1);
  WAITV4();
  SBAR();

  int c0 = 0, c1 = 1, c2 = 2;
  for (int t = 0; t < NT; ++t) {
    const bool st = (t + 2) < NT;
    if (st) stage(t + 2, c2);
    const _Float16* sb = lds + c0 * 16384;
    half8 ah[8], bh[4];
#pragma unroll
    for (int f = 0; f < 8; ++f)
      ah[f] = *(const half8*)(sb + (wr * 128 + f * 16 + lr) * 32 + rswz8);
#pragma unroll
    for (int f = 0; f < 4; ++f)
      bh[f] = *(const half8*)(sb + 8192 + (wc * 64 + f * 16 + lr) * 32 + rswz8);
    __builtin_amdgcn_s_setprio(1);
#pragma unroll
    for (int fm = 0; fm < 8; ++fm)
#pragma unroll
      for (int fn = 0; fn < 4; ++fn)
        acc[fm][fn] = __builtin_amdgcn_mfma_f32_16x16x32_f16(ah[fm], bh[fn], acc[fm][fn], 0, 0, 0);
    __builtin_amdgcn_s_setprio(0);
    if (st) { WAITV4(); } else if (t + 1 < NT) { WAITV0(); }
    SBAR();
    int tmp = c0; c0 = c1; c1 = c2; c2 = tmp;
  }

  if constexpr (MODE == 0) {
    // tok epilogue: +bias, store f16 hi, accumulate ||t||^2
#pragma unroll
    for (int fm = 0; fm < 8; ++fm) {
#pragma unroll
      for (int j = 0; j < 4; ++j) {
        int row = wr * 128 + fm * 16 + lk * 4 + j;
        size_t m = (size_t)m0 + row;
        float v2 = 0.f;
#pragma unroll
        for (int fn = 0; fn < 4; ++fn) {
          int col = n0 + wc * 64 + fn * 16 + lr;
          float v = acc[fm][fn][j] + vec[col];
          v2 += v * v;
          outh[m * (size_t)D + col] = (_Float16)v;
        }
#pragma unroll
        for (int mk = 1; mk < 16; mk <<= 1) v2 += __shfl_xor(v2, mk, 64);
        if (lr == 0) atomicAdd(&t2[m], v2);
      }
    }
  } else {
    // score epilogue: top-2 of mval over this wave's 64 codes -> private slot
#pragma unroll
    for (int fm = 0; fm < 8; ++fm) {
#pragma unroll
      for (int j = 0; j < 4; ++j) {
        int row = wr * 128 + fm * 16 + lk * 4 + j;
        size_t m = (size_t)m0 + row;
        float b1 = 3.4e38f, bb2 = 3.4e38f;
        int i1 = 0x7FFFFFFF;
#pragma unroll
        for (int fn = 0; fn < 4; ++fn) {
          int col = n0 + wc * 64 + fn * 16 + lr;
          float mv = vec[col] - 2.0f * acc[fm][fn][j];
          if (mv < b1) { bb2 = b1; b1 = mv; i1 = col; }
          else if (mv < bb2) { bb2 = mv; }
        }
#pragma unroll
        for (int mk = 1; mk < 16; mk <<= 1) {
          float ob1 = __shfl_xor(b1, mk, 64);
          float ob2 = __shfl_xor(bb2, mk, 64);
          int oi = __shfl_xor(i1, mk, 64);
          if (ob1 < b1) { bb2 = fminf(b1, ob2); b1 = ob1; i1 = oi; }
          else { bb2 = fminf(bb2, ob1); }
        }
        if (lr == 0) {
          unsigned long long key = ((unsigned long long)f32_to_key(b1) << 32) | (unsigned)i1;
          skKey[m * 32 + nb * 4 + wc] = key;
          skSnd[m * 32 + nb * 4 + wc] = bb2;
        }
      }
    }
  }
}

// ---------------- flag: global top-2 over 32 slots, margin test, compact ----------------
__global__ __launch_bounds__(256) void k_flag(const unsigned long long* __restrict__ skKey,
                                              const float* __restrict__ skSnd,
                                              unsigned long long* __restrict__ keys,
                                              int* __restrict__ list, int* __restrict__ counter) {
  int m = blockIdx.x * 256 + threadIdx.x;
  unsigned long long best = ~0ull;
  int bsl = 0;
#pragma unroll
  for (int sl = 0; sl < 32; ++sl) {
    unsigned long long k = skKey[(size_t)m * 32 + sl];
    if (k < best) { best = k; bsl = sl; }
  }
  float b1 = key_to_f32((unsigned)(best >> 32));
  float second = skSnd[(size_t)m * 32 + bsl];
#pragma unroll
  for (int sl = 0; sl < 32; ++sl) {
    if (sl != bsl) second = fminf(second, key_to_f32((unsigned)(skKey[(size_t)m * 32 + sl] >> 32)));
  }
  keys[m] = best;
  if (second - b1 < TAU) {
    int p = atomicAdd(counter, 1);
    if (p < CAP) list[p] = m;
  }
}

// ---------------- tok_fix: recompute TRUE tokens (3-product) for flagged rows ----------------
// gather-GEMM: A rows = xh/xl[list[m]], B = wh/wl, K=2048; writes tokh2/tokl2 (dense CAP rows).
__global__ __launch_bounds__(256) void k_tok_fix(
    const _Float16* __restrict__ xh, const _Float16* __restrict__ xl,
    const _Float16* __restrict__ wh, const _Float16* __restrict__ wl,
    const float* __restrict__ b_in, const int* __restrict__ list,
    const int* __restrict__ counter,
    _Float16* __restrict__ tokh2, _Float16* __restrict__ tokl2) {
  const int count = min(counter[0], CAP);
  const int m0 = blockIdx.y * 128;
  if (m0 >= count) return;
  __shared__ _Float16 sAh[128 * 32], sAl[128 * 32], sBh[128 * 32], sBl[128 * 32];
  const int n0 = blockIdx.x * 128;
  const int tid = threadIdx.x, lane = tid & 63, w = tid >> 6;
  const int wr = w >> 1, wc = w & 1, lr = lane & 15, lk = lane >> 4;
  f32x4 acc[4][4] = {};

  const int g0 = w * 128 + lane, g1 = g0 + 64;
  const int rA0 = g0 >> 2, cA0 = g0 & 3, rA1 = g1 >> 2, cA1 = g1 & 3;
  const int lb0 = (w * 128) * 16, lb1 = (w * 128 + 64) * 16;
  const int tk0 = list[min(m0 + rA0, count - 1)];
  const int tk1 = list[min(m0 + rA1, count - 1)];

  for (int kt = 0; kt < KIN / 32; ++kt) {
    const int k0 = kt * 32;
    gload16(xh + (size_t)tk0 * KIN + k0 + cA0 * 8, (char*)sAh + lb0);
    gload16(xh + (size_t)tk1 * KIN + k0 + cA1 * 8, (char*)sAh + lb1);
    gload16(xl + (size_t)tk0 * KIN + k0 + cA0 * 8, (char*)sAl + lb0);
    gload16(xl + (size_t)tk1 * KIN + k0 + cA1 * 8, (char*)sAl + lb1);
    gload16(wh + (size_t)(n0 + rA0) * KIN + k0 + cA0 * 8, (char*)sBh + lb0);
    gload16(wh + (size_t)(n0 + rA1) * KIN + k0 + cA1 * 8, (char*)sBh + lb1);
    gload16(wl + (size_t)(n0 + rA0) * KIN + k0 + cA0 * 8, (char*)sBl + lb0);
    gload16(wl + (size_t)(n0 + rA1) * KIN + k0 + cA1 * 8, (char*)sBl + lb1);
    __syncthreads();
    half8 ah[4], al2[4], bh[4], bl2[4];
#pragma unroll
    for (int f = 0; f < 4; ++f) {
      ah[f]  = *(const half8*)(sAh + (wr * 64 + f * 16 + lr) * 32 + lk * 8);
      al2[f] = *(const half8*)(sAl + (wr * 64 + f * 16 + lr) * 32 + lk * 8);
      bh[f]  = *(const half8*)(sBh + (wc * 64 + f * 16 + lr) * 32 + lk * 8);
      bl2[f] = *(const half8*)(sBl + (wc * 64 + f * 16 + lr) * 32 + lk * 8);
    }
#pragma unroll
    for (int fm = 0; fm < 4; ++fm)
#pragma unroll
      for (int fn = 0; fn < 4; ++fn) {
        acc[fm][fn] = __builtin_amdgcn_mfma_f32_16x16x32_f16(ah[fm], bh[fn], acc[fm][fn], 0, 0, 0);
        acc[fm][fn] = __builtin_amdgcn_mfma_f32_16x16x32_f16(ah[fm], bl2[fn], acc[fm][fn], 0, 0, 0);
        acc[fm][fn] = __builtin_amdgcn_mfma_f32_16x16x32_f16(al2[fm], bh[fn], acc[fm][fn], 0, 0, 0);
      }
    __syncthreads();
  }
#pragma unroll
  for (int fm = 0; fm < 4; ++fm) {
#pragma unroll
    for (int j = 0; j < 4; ++j) {
      int row = wr * 64 + fm * 16 + lk * 4 + j;
      if (m0 + row >= count) continue;
#pragma unroll
      for (int fn = 0; fn < 4; ++fn) {
        int col = n0 + wc * 64 + fn * 16 + lr;
        float v = acc[fm][fn][j] + b_in[col];
        _Float16 h = (_Float16)v;
        tokh2[(size_t)(m0 + row) * D + col] = h;
        tokl2[(size_t)(m0 + row) * D + col] = (_Float16)(v - (float)h);
      }
    }
  }
}

// ---------------- rescore: 3-product exact scoring of flagged tokens ----------------
__global__ __launch_bounds__(256) void k_rescore(
    const _Float16* __restrict__ tokh2, const _Float16* __restrict__ tokl2,
    const _Float16* __restrict__ eh, const _Float16* __restrict__ el,
    const float* __restrict__ e2c, const int* __restrict__ list,
    const int* __restrict__ counter,
    unsigned long long* __restrict__ keys2) {
  const int count = min(counter[0], CAP);
  const int m0 = blockIdx.y * 128;
  if (m0 >= count) return;
  __shared__ _Float16 sAh[128 * 32], sAl[128 * 32], sBh[128 * 32], sBl[128 * 32];
  const int n0 = blockIdx.x * 128;
  const int tid = threadIdx.x, lane = tid & 63, w = tid >> 6;
  const int wr = w >> 1, wc = w & 1, lr = lane & 15, lk = lane >> 4;
  f32x4 acc[4][4] = {};

  const int g0 = w * 128 + lane, g1 = g0 + 64;
  const int rA0 = g0 >> 2, cA0 = g0 & 3, rA1 = g1 >> 2, cA1 = g1 & 3;
  const int lb0 = (w * 128) * 16, lb1 = (w * 128 + 64) * 16;

  for (int kt = 0; kt < D / 32; ++kt) {
    const int k0 = kt * 32;
    gload16(tokh2 + (size_t)(m0 + rA0) * D + k0 + cA0 * 8, (char*)sAh + lb0);
    gload16(tokh2 + (size_t)(m0 + rA1) * D + k0 + cA1 * 8, (char*)sAh + lb1);
    gload16(tokl2 + (size_t)(m0 + rA0) * D + k0 + cA0 * 8, (char*)sAl + lb0);
    gload16(tokl2 + (size_t)(m0 + rA1) * D + k0 + cA1 * 8, (char*)sAl + lb1);
    gload16(eh + (size_t)(n0 + rA0) * D + k0 + cA0 * 8, (char*)sBh + lb0);
    gload16(eh + (size_t)(n0 + rA1) * D + k0 + cA1 * 8, (char*)sBh + lb1);
    gload16(el + (size_t)(n0 + rA0) * D + k0 + cA0 * 8, (char*)sBl + lb0);
    gload16(el + (size_t)(n0 + rA1) * D + k0 + cA1 * 8, (char*)sBl + lb1);
    __syncthreads();
    half8 ah[4], al2[4], bh[4], bl2[4];
#pragma unroll
    for (int f = 0; f < 4; ++f) {
      ah[f]  = *(const half8*)(sAh + (wr * 64 + f * 16 + lr) * 32 + lk * 8);
      al2[f] = *(const half8*)(sAl + (wr * 64 + f * 16 + lr) * 32 + lk * 8);
      bh[f]  = *(const half8*)(sBh + (wc * 64 + f * 16 + lr) * 32 + lk * 8);
      bl2[f] = *(const half8*)(sBl + (wc * 64 + f * 16 + lr) * 32 + lk * 8);
    }
#pragma unroll
    for (int fm = 0; fm < 4; ++fm)
#pragma unroll
      for (int fn = 0; fn < 4; ++fn) {
        acc[fm][fn] = __builtin_amdgcn_mfma_f32_16x16x32_f16(ah[fm], bh[fn], acc[fm][fn], 0, 0, 0);
        acc[fm][fn] = __builtin_amdgcn_mfma_f32_16x16x32_f16(ah[fm], bl2[fn], acc[fm][fn], 0, 0, 0);
        acc[fm][fn] = __builtin_amdgcn_mfma_f32_16x16x32_f16(al2[fm], bh[fn], acc[fm][fn], 0, 0, 0);
      }
    __syncthreads();
  }
#pragma unroll
  for (int fm = 0; fm < 4; ++fm) {
#pragma unroll
    for (int j = 0; j < 4; ++j) {
      int row = wr * 64 + fm * 16 + lk * 4 + j;
      if (m0 + row >= count) continue;
      int tm = list[m0 + row];
      float best = 3.4e38f;
      int bidx = 0x7FFFFFFF;
#pragma unroll
      for (int fn = 0; fn < 4; ++fn) {
        int col = n0 + wc * 64 + fn * 16 + lr;
        float mv = e2c[col] - 2.0f * acc[fm][fn][j];
        if (mv < best) { best = mv; bidx = col; }
      }
#pragma unroll
      for (int mk = 1; mk < 16; mk <<= 1) {
        float ob = __shfl_xor(best, mk, 64);
        int oi = __shfl_xor(bidx, mk, 64);
        if (ob < best || (ob == best && oi < bidx)) { best = ob; bidx = oi; }
      }
      if (lr == 0) {
        unsigned long long key = ((unsigned long long)f32_to_key(best) << 32) | (unsigned)bidx;
        atomicMin(&keys2[tm], key);
      }
    }
  }
}

__global__ __launch_bounds__(256) void k_merge(unsigned long long* __restrict__ keys,
                                               const unsigned long long* __restrict__ keys2) {
  int m = blockIdx.x * 256 + threadIdx.x;
  unsigned long long k2 = keys2[m];
  if (k2 != ~0ull) keys[m] = k2;
}

// ---------------- GEMM C: out = embed[idx] * w_out^T (unchanged) ----------------
__global__ __launch_bounds__(256) void k_gemm_out(
    const _Float16* __restrict__ eh, const unsigned long long* __restrict__ keys,
    const _Float16* __restrict__ woh, const float* __restrict__ b_out,
    const float* __restrict__ mask, float* __restrict__ out) {
  __shared__ _Float16 sA[128 * 32], sB[128 * 32];
  __shared__ float sC[32 * 129];
  const int n0 = blockIdx.x * 128, m0 = blockIdx.y * 128;
  const int tid = threadIdx.x, lane = tid & 63, w = tid >> 6;
  const int wr = w >> 1, wc = w & 1, lr = lane & 15, lk = lane >> 4;
  f32x4 acc[4][4] = {};

  const int g0 = w * 128 + lane, g1 = g0 + 64;
  const int rA0 = g0 >> 2, cA0 = g0 & 3, rA1 = g1 >> 2, cA1 = g1 & 3;
  const int lb0 = (w * 128) * 16, lb1 = (w * 128 + 64) * 16;
  const unsigned i0 = (unsigned)(keys[m0 + rA0] & 0xFFFFFFFFull);
  const unsigned i1 = (unsigned)(keys[m0 + rA1] & 0xFFFFFFFFull);
  const _Float16* srcA0 = eh + (size_t)i0 * D + cA0 * 8;
  const _Float16* srcA1 = eh + (size_t)i1 * D + cA1 * 8;

  for (int kt = 0; kt < D / 32; ++kt) {
    const int k0 = kt * 32;
    gload16(srcA0 + k0, (char*)sA + lb0);
    gload16(srcA1 + k0, (char*)sA + lb1);
    gload16(woh + (size_t)(n0 + rA0) * D + k0 + cA0 * 8, (char*)sB + lb0);
    gload16(woh + (size_t)(n0 + rA1) * D + k0 + cA1 * 8, (char*)sB + lb1);
    __syncthreads();
    half8 a[4], b[4];
#pragma unroll
    for (int f = 0; f < 4; ++f) {
      a[f] = *(const half8*)(sA + (wr * 64 + f * 16 + lr) * 32 + lk * 8);
      b[f] = *(const half8*)(sB + (wc * 64 + f * 16 + lr) * 32 + lk * 8);
    }
#pragma unroll
    for (int fm = 0; fm < 4; ++fm)
#pragma unroll
      for (int fn = 0; fn < 4; ++fn)
        acc[fm][fn] = __builtin_amdgcn_mfma_f32_16x16x32_f16(a[fm], b[fn], acc[fm][fn], 0, 0, 0);
    __syncthreads();
  }
  for (int ch = 0; ch < 4; ++ch) {
    __syncthreads();
    if (wr == (ch >> 1)) {
      int fb = (ch & 1) * 2;
#pragma unroll
      for (int f2 = 0; f2 < 2; ++f2) {
        int fm = fb + f2;
#pragma unroll
        for (int fn = 0; fn < 4; ++fn)
#pragma unroll
          for (int j = 0; j < 4; ++j) {
            int lrow = f2 * 16 + lk * 4 + j;
            int col = wc * 64 + fn * 16 + lr;
            sC[lrow * 129 + col] = acc[fm][fn][j] + b_out[n0 + col];
          }
      }
    }
    __syncthreads();
    const int mbase = m0 + ch * 32;
    const int b = mbase >> 11;
    const int l0 = mbase & 2047;
    const float mval = mask[(size_t)b * TLEN + 2 * l0 + lane];
    for (int oo = 0; oo < 32; ++oo) {
      int ocol = w * 32 + oo;
      float v = sC[(lane >> 1) * 129 + ocol];
      out[((size_t)(b * D + n0 + ocol)) * TLEN + 2 * l0 + lane] = v * mval;
    }
  }
}

// ---------------- loss ----------------
__global__ __launch_bounds__(256) void k_loss(const unsigned long long* __restrict__ keys,
                                              const float* __restrict__ t2,
                                              double* __restrict__ acc) {
  int m = blockIdx.x * 256 + threadIdx.x;
  unsigned long long k = keys[m];
  float mval = key_to_f32((unsigned)(k >> 32));
  double c = (double)mval + 1024.0 + (double)t2[m];
#pragma unroll
  for (int mk = 1; mk < 64; mk <<= 1) c += __shfl_xor(c, mk, 64);
  __shared__ double part[4];
  if ((threadIdx.x & 63) == 0) part[threadIdx.x >> 6] = c;
  __syncthreads();
  if (threadIdx.x == 0) atomicAdd(acc, part[0] + part[1] + part[2] + part[3]);
}

__global__ void k_finalize(const double* __restrict__ acc, float* __restrict__ dst) {
  if (threadIdx.x == 0 && blockIdx.x == 0) *dst = (float)(*acc * (1.0 / 16777216.0));
}

// ---------------- host ----------------
extern "C" void kernel_launch(void* const* d_in, const int* in_sizes, int n_in,
                              void* d_out, int out_size, void* d_ws, size_t ws_size,
                              hipStream_t stream) {
  (void)in_sizes; (void)n_in; (void)out_size;
  const float* x      = (const float*)d_in[0];
  const float* xmask  = (const float*)d_in[1];
  const float* w_in   = (const float*)d_in[2];
  const float* b_in   = (const float*)d_in[3];
  const float* embed  = (const float*)d_in[4];
  const float* w_out  = (const float*)d_in[5];
  const float* b_out  = (const float*)d_in[6];
  float* out = (float*)d_out;

  // x hi/lo splits live in d_out (dead until k_gemm_out; k_tok_fix runs before it)
  _Float16* xh = (_Float16*)d_out;
  _Float16* xl = xh + (size_t)MTOK * KIN;

  char* p = (char*)d_ws;
  auto take = [&](size_t sz) { char* r = p; p += (sz + 255) & ~(size_t)255; return r; };
  _Float16* wh    = (_Float16*)take((size_t)D * KIN * 2);
  _Float16* wl    = (_Float16*)take((size_t)D * KIN * 2);
  _Float16* eh    = (_Float16*)take((size_t)NCODE * D * 2);
  _Float16* el    = (_Float16*)take((size_t)NCODE * D * 2);
  _Float16* woh   = (_Float16*)take((size_t)D * D * 2);
  float* e2c      = (float*)take((size_t)NCODE * 4);
  _Float16* tokh  = (_Float16*)take((size_t)MTOK * D * 2);
  _Float16* tokh2 = (_Float16*)take((size_t)CAP * D * 2);
  _Float16* tokl2 = (_Float16*)take((size_t)CAP * D * 2);
  float* t2       = (float*)take((size_t)MTOK * 4);
  unsigned long long* keys  = (unsigned long long*)take((size_t)MTOK * 8);
  unsigned long long* keys2 = (unsigned long long*)take((size_t)MTOK * 8);
  unsigned long long* skKey = (unsigned long long*)take((size_t)MTOK * 32 * 8);
  float* skSnd    = (float*)take((size_t)MTOK * 32 * 4);
  int* list       = (int*)take((size_t)CAP * 4);
  int* counter    = (int*)take(256);
  double* lossacc = (double*)take(256);
  if ((size_t)(p - (char*)d_ws) > ws_size) return;

  hipMemsetAsync(keys2, 0xFF, (size_t)MTOK * 8, stream);
  hipMemsetAsync(t2, 0, (size_t)MTOK * 4, stream);
  hipMemsetAsync(list, 0, (size_t)CAP * 4, stream);
  hipMemsetAsync(counter, 0, 256, stream);
  hipMemsetAsync(lossacc, 0, 8, stream);

  k_pack_x<<<dim3(64, 32, 8), 256, 0, stream>>>(x, xh, xl);
  k_split<<<(D * KIN + 255) / 256, 256, 0, stream>>>(w_in, wh, wl, D * KIN);
  k_split<<<(NCODE * D + 255) / 256, 256, 0, stream>>>(embed, eh, el, NCODE * D);
  k_tohalf<<<(D * D + 255) / 256, 256, 0, stream>>>(w_out, woh, D * D);
  k_e2<<<NCODE / 4, 256, 0, stream>>>(embed, e2c);

  // tok1: hh-only tokens, M=16384 x N=1024 (256x256 tiles -> 64x4 = 256 blocks)
  k_gemm_hh<KIN, 2, 0><<<256, 512, 0, stream>>>(xh, wh, b_in, tokh, t2, nullptr, nullptr);
  // score1: hh-only scores + top-2, M=16384 x N=2048 (64x8 = 512 blocks)
  k_gemm_hh<D, 3, 1><<<512, 512, 0, stream>>>(tokh, eh, e2c, nullptr, nullptr, skKey, skSnd);
  k_flag<<<MTOK / 256, 256, 0, stream>>>(skKey, skSnd, keys, list, counter);
  // recompute true tokens for flagged rows, then exact rescore (both count-guarded)
  k_tok_fix<<<dim3(D / 128, CAP / 128), 256, 0, stream>>>(xh, xl, wh, wl, b_in, list, counter, tokh2, tokl2);
  k_rescore<<<dim3(NCODE / 128, CAP / 128), 256, 0, stream>>>(tokh2, tokl2, eh, el, e2c, list, counter, keys2);
  k_merge<<<MTOK / 256, 256, 0, stream>>>(keys, keys2);

  k_gemm_out<<<dim3(D / 128, MTOK / 128), 256, 0, stream>>>(eh, keys, woh, b_out, xmask, out);

  k_loss<<<MTOK / 256, 256, 0, stream>>>(keys, t2, lossacc);
  k_finalize<<<1, 64, 0, stream>>>(lossacc, out + (size_t)MTOK * KIN);
}